// Round 1
// baseline (734.564 us; speedup 1.0000x reference)
//
#include <hip/hip_runtime.h>

#define NHID   512
#define NCLS   250
#define CHUNK  200
#define NTOK   2048
#define NOUT   (NCLS + CHUNK)    // 450
#define RPH    225               // rows per half (450/2)
#define NBLK   (NCLS * 2)        // 500 blocks
#define NTHR   1024

// Combine two 64-lane partial-sum registers (tokens A and B) in one butterfly
// stage of distance d: lanes with (lane&d)==0 end up holding pair-sums of a,
// lanes with (lane&d)!=0 pair-sums of b.
__device__ __forceinline__ float comb(float a, float b, int d, int lane) {
    float ta = __shfl_xor(a, d);
    float tb = __shfl_xor(b, d);
    return (lane & d) ? (b + tb) : (a + ta);
}

__global__ __launch_bounds__(NTHR, 8)
void cbd_kernel(const float* __restrict__ x,
                const float* __restrict__ Wc,
                const float* __restrict__ bc,
                const float* __restrict__ Ww,
                const float* __restrict__ bw,
                const int*   __restrict__ cls_idx,
                float* __restrict__ out)
{
    __shared__ int   tok[NTOK];
    __shared__ float xs[16 * NHID];   // 32 KB: up to 16 tokens' x rows
    __shared__ int   cnt;

    const int tid  = threadIdx.x;
    const int c    = blockIdx.x >> 1;
    const int half = blockIdx.x & 1;

    // ---- build token list for class c (all blocks of this class do it; cheap) ----
    if (tid == 0) cnt = 0;
    __syncthreads();
    for (int i = tid; i < NTOK; i += NTHR)
        if (cls_idx[i] == c) { int p = atomicAdd(&cnt, 1); tok[p] = i; }
    __syncthreads();
    const int count = cnt;
    if (count == 0) return;

    const int w = tid >> 6;   // wave 0..15
    const int l = tid & 63;   // lane 0..63
    const int rbase = half * RPH;

    for (int tbase = 0; tbase < count; tbase += 16) {
        const int nt   = min(16, count - tbase);
        const int noct = (nt + 7) >> 3;

        __syncthreads();  // previous chunk's xs reads done
        // ---- stage up to 16 token x-rows into LDS (coalesced float4) ----
        for (int idx = tid; idx < 16 * (NHID / 4); idx += NTHR) {
            int row = idx >> 7;            // /128 f4 per row
            int off = (idx & 127) << 2;    // float offset
            if (row < nt) {
                float4 v = *(const float4*)&x[(size_t)tok[tbase + row] * NHID + off];
                *(float4*)&xs[row * NHID + off] = v;
            }
        }
        __syncthreads();

        // ---- pull x slices into registers: lane l owns h in [4l,4l+4) u [256+4l,+4) ----
        float4 X0[2][8], X1[2][8];
        #pragma unroll
        for (int o = 0; o < 2; ++o)
            #pragma unroll
            for (int t = 0; t < 8; ++t) {
                X0[o][t] = *(const float4*)&xs[(o * 8 + t) * NHID + 4 * l];
                X1[o][t] = *(const float4*)&xs[(o * 8 + t) * NHID + 256 + 4 * l];
            }
        int mytok[2];
        #pragma unroll
        for (int o = 0; o < 2; ++o) {
            int ti = tbase + o * 8 + (l & 7);
            mytok[o] = tok[ti < count ? ti : 0];
        }

        // ---- stream this half's weight rows: wave w takes rows w, w+16, ... ----
        // virtual row r: r<200 -> Ww[c][r]; else -> Wc[r-200]
        auto rowsrc = [&](int i) -> const float* {
            int rh = w + 16 * i; if (rh >= RPH) rh = RPH - 1;   // clamp (masked later)
            int r = rbase + rh;
            return (r < CHUNK) ? (Ww + ((size_t)c * CHUNK + r) * NHID)
                               : (Wc + (size_t)(r - CHUNK) * NHID);
        };

        float4 P0[2], P1[2];
        {
            const float* s0 = rowsrc(0);
            P0[0] = *(const float4*)(s0 + 4 * l);
            P1[0] = *(const float4*)(s0 + 256 + 4 * l);
            const float* s1 = rowsrc(1);
            P0[1] = *(const float4*)(s1 + 4 * l);
            P1[1] = *(const float4*)(s1 + 256 + 4 * l);
        }

        for (int i = 0; i < 15; ++i) {
            const int rh = w + 16 * i;
            float4 a0 = P0[i & 1], a1 = P1[i & 1];
            if (i + 2 < 15) {   // prefetch next-next row into the ring
                const float* sn = rowsrc(i + 2);
                P0[i & 1] = *(const float4*)(sn + 4 * l);
                P1[i & 1] = *(const float4*)(sn + 256 + 4 * l);
            }
            if (rh < RPH) {
                const int r    = rbase + rh;
                const int col  = (r < CHUNK) ? (NCLS + r) : (r - CHUNK);
                const float bias = (r < CHUNK) ? bw[c * CHUNK + r] : bc[r - CHUNK];

                #pragma unroll
                for (int o = 0; o < 2; ++o) {
                    if (o < noct) {
                        float acc[8];
                        #pragma unroll
                        for (int t = 0; t < 8; ++t) {
                            float4 xa = X0[o][t], xb = X1[o][t];
                            float s = a0.x * xa.x;
                            s = fmaf(a0.y, xa.y, s);
                            s = fmaf(a0.z, xa.z, s);
                            s = fmaf(a0.w, xa.w, s);
                            s = fmaf(a1.x, xb.x, s);
                            s = fmaf(a1.y, xb.y, s);
                            s = fmaf(a1.z, xb.z, s);
                            s = fmaf(a1.w, xb.w, s);
                            acc[t] = s;
                        }
                        // batched 64-lane reduction of 8 token accumulators
                        float c0 = comb(acc[0], acc[1], 1, l);
                        float c1 = comb(acc[2], acc[3], 1, l);
                        float c2 = comb(acc[4], acc[5], 1, l);
                        float c3 = comb(acc[6], acc[7], 1, l);
                        float d0 = comb(c0, c1, 2, l);
                        float d1 = comb(c2, c3, 2, l);
                        float e  = comb(d0, d1, 4, l);
                        e += __shfl_xor(e, 8);
                        e += __shfl_xor(e, 16);
                        e += __shfl_xor(e, 32);
                        // lane t (0..7) now holds token (tbase+o*8+t)'s full dot
                        if (l < 8 && (tbase + o * 8 + l) < count)
                            out[(size_t)mytok[o] * NOUT + col] = e + bias;
                    }
                }
            }
        }
    }
}

extern "C" void kernel_launch(void* const* d_in, const int* in_sizes, int n_in,
                              void* d_out, int out_size, void* d_ws, size_t ws_size,
                              hipStream_t stream) {
    const float* x   = (const float*)d_in[0];
    const float* Wc  = (const float*)d_in[1];
    const float* bc  = (const float*)d_in[2];
    const float* Ww  = (const float*)d_in[3];
    const float* bw  = (const float*)d_in[4];
    const int*   cls = (const int*)d_in[5];
    float* out = (float*)d_out;
    hipLaunchKernelGGL(cbd_kernel, dim3(NBLK), dim3(NTHR), 0, stream,
                       x, Wc, bc, Ww, bw, cls, out);
}

// Round 3
// 239.615 us; speedup vs baseline: 3.0656x; 3.0656x over previous
//
#include <hip/hip_runtime.h>

#define NHID   512
#define NCLS   250
#define CHUNK  200
#define NTOK   2048
#define NOUT   (NCLS + CHUNK)    // 450
#define NBLK   (NCLS * 2)        // 500 blocks: (class, half)
#define NTHR   256               // 4 waves

// butterfly stage within 32-lane groups: v += lane(v ^ D)
template <int PAT>
__device__ __forceinline__ float swz_add(float v) {
    return v + __int_as_float(__builtin_amdgcn_ds_swizzle(__float_as_int(v), PAT));
}

// Merge two partial-sum regs (tokens A,B) at butterfly distance D using ONE
// cross-lane op: low lanes keep a-pairs, high lanes keep b-pairs.
template <int D>
__device__ __forceinline__ float comb(float a, float b, int lane) {
    const bool hi = (lane & D) != 0;
    float keep = hi ? b : a;
    float send = hi ? a : b;
    float t = __int_as_float(
        __builtin_amdgcn_ds_swizzle(__float_as_int(send), (D << 10) | 0x1F));
    return keep + t;
}

__global__ __launch_bounds__(NTHR, 2)   // VGPR cap 256; ~2 waves/EU target
void cbd_kernel(const float* __restrict__ x,
                const float* __restrict__ Wc,
                const float* __restrict__ bc,
                const float* __restrict__ Ww,
                const float* __restrict__ bw,
                const int*   __restrict__ cls_idx,
                float* __restrict__ out)
{
    __shared__ int   tok[NTOK];
    __shared__ float xs[16 * NHID];   // 32 KB: up to 16 tokens' x rows
    __shared__ int   cnt;

    const int tid  = threadIdx.x;
    const int c    = blockIdx.x >> 1;
    const int half = blockIdx.x & 1;

    // ---- build token list for class c ----
    if (tid == 0) cnt = 0;
    __syncthreads();
    for (int i = tid; i < NTOK; i += NTHR)
        if (cls_idx[i] == c) { int p = atomicAdd(&cnt, 1); tok[p] = i; }
    __syncthreads();
    const int count = cnt;
    if (count == 0) return;

    const int w = tid >> 6;   // wave 0..3
    const int l = tid & 63;   // lane

    for (int tbase = 0; tbase < count; tbase += 16) {
        const int nt   = min(16, count - tbase);
        const int noct = (nt + 7) >> 3;

        __syncthreads();  // previous chunk's xs reads done
        // ---- stage up to 16 token x-rows into LDS (coalesced float4) ----
        for (int idx = tid; idx < 16 * (NHID / 4); idx += NTHR) {
            int row = idx >> 7;            // /128 f4 per row
            int off = (idx & 127) << 2;    // float offset
            if (row < nt) {
                float4 v = *(const float4*)&x[(size_t)tok[tbase + row] * NHID + off];
                *(float4*)&xs[row * NHID + off] = v;
            } else {
                float4 z = {0.f, 0.f, 0.f, 0.f};
                *(float4*)&xs[row * NHID + off] = z;
            }
        }
        __syncthreads();

        // ---- x slices to registers: lane l owns h in [4l,4l+4) u [256+4l,..) ----
        float4 X0[2][8], X1[2][8];
        #pragma unroll
        for (int o = 0; o < 2; ++o)
            #pragma unroll
            for (int t = 0; t < 8; ++t) {
                X0[o][t] = *(const float4*)&xs[(o * 8 + t) * NHID + 4 * l];
                X1[o][t] = *(const float4*)&xs[(o * 8 + t) * NHID + 256 + 4 * l];
            }
        int mytok[2];
        #pragma unroll
        for (int o = 0; o < 2; ++o) {
            int ti = tbase + o * 8 + (l & 7);
            mytok[o] = tok[ti < count ? ti : 0];
        }

        // ---- stream this half's weight rows; r = 2*(w+4i)+half ----
        auto loadrow = [&](int i, float4& R0, float4& R1) {
            int rh = w + 4 * i; if (rh > 224) rh = 224;   // clamp overshoot
            int r  = 2 * rh + half;
            const float* p = (r < CHUNK) ? (Ww + ((size_t)c * CHUNK + r) * NHID)
                                         : (Wc + (size_t)(r - CHUNK) * NHID);
            R0 = *(const float4*)(p + 4 * l);
            R1 = *(const float4*)(p + 256 + 4 * l);
        };

        auto work = [&](int i, float4 a0, float4 a1) {
            const int rh = w + 4 * i;           // valid: caller guarantees < 225
            const int r  = 2 * rh + half;
            int col; float bias;
            if (r < CHUNK) { col = NCLS + r;  bias = bw[c * CHUNK + r]; }
            else           { col = r - CHUNK; bias = bc[r - CHUNK]; }

            #pragma unroll
            for (int o = 0; o < 2; ++o) {
                if (o < noct) {
                    float acc[8];
                    #pragma unroll
                    for (int t = 0; t < 8; ++t) {
                        float4 xa = X0[o][t], xb = X1[o][t];
                        float s = a0.x * xa.x;
                        s = fmaf(a0.y, xa.y, s);
                        s = fmaf(a0.z, xa.z, s);
                        s = fmaf(a0.w, xa.w, s);
                        s = fmaf(a1.x, xb.x, s);
                        s = fmaf(a1.y, xb.y, s);
                        s = fmaf(a1.z, xb.z, s);
                        s = fmaf(a1.w, xb.w, s);
                        acc[t] = s;
                    }
                    float c0 = comb<1>(acc[0], acc[1], l);
                    float c1 = comb<1>(acc[2], acc[3], l);
                    float c2 = comb<1>(acc[4], acc[5], l);
                    float c3 = comb<1>(acc[6], acc[7], l);
                    float d0 = comb<2>(c0, c1, l);
                    float d1 = comb<2>(c2, c3, l);
                    float e  = comb<4>(d0, d1, l);
                    e = swz_add<(8  << 10) | 0x1F>(e);
                    e = swz_add<(16 << 10) | 0x1F>(e);
                    e += __shfl_xor(e, 32, 64);
                    // lane t (0..7) holds token (tbase+o*8+t)'s dot
                    if (l < 8 && (tbase + o * 8 + l) < count)
                        out[(size_t)mytok[o] * NOUT + col] = e + bias;
                }
            }
        };

        const int nr = (224 - w) / 4 + 1;   // rows this wave: 57 or 56
        float4 A0, A1, B0, B1, C0, C1;
        loadrow(0, A0, A1);
        loadrow(1, B0, B1);
        loadrow(2, C0, C1);
        int i = 0;
        for (; i + 3 <= nr; i += 3) {
            work(i,     A0, A1); loadrow(i + 3, A0, A1);
            work(i + 1, B0, B1); loadrow(i + 4, B0, B1);
            work(i + 2, C0, C1); loadrow(i + 5, C0, C1);
        }
        if (i     < nr) work(i,     A0, A1);
        if (i + 1 < nr) work(i + 1, B0, B1);
    }
}

extern "C" void kernel_launch(void* const* d_in, const int* in_sizes, int n_in,
                              void* d_out, int out_size, void* d_ws, size_t ws_size,
                              hipStream_t stream) {
    const float* x   = (const float*)d_in[0];
    const float* Wc  = (const float*)d_in[1];
    const float* bc  = (const float*)d_in[2];
    const float* Ww  = (const float*)d_in[3];
    const float* bw  = (const float*)d_in[4];
    const int*   cls = (const int*)d_in[5];
    float* out = (float*)d_out;
    hipLaunchKernelGGL(cbd_kernel, dim3(NBLK), dim3(NTHR), 0, stream,
                       x, Wc, bc, Ww, bw, cls, out);
}